// Round 5
// baseline (2333.868 us; speedup 1.0000x reference)
//
#include <hip/hip_runtime.h>
#include <cstdint>

typedef __attribute__((ext_vector_type(8))) short          bf16x8;
typedef __attribute__((ext_vector_type(8))) unsigned short u16x8;
typedef __attribute__((ext_vector_type(4))) float          f32x4;

__device__ __forceinline__ unsigned short f2bf(float x) {
    union { float f; unsigned u; } v; v.f = x;
    unsigned r = v.u + 0x7FFF + ((v.u >> 16) & 1);   // RNE
    return (unsigned short)(r >> 16);
}
__device__ __forceinline__ float bf2f(unsigned short b) {
    union { float f; unsigned u; } v; v.u = ((unsigned)b) << 16;
    return v.f;
}

#define EB   128  // edges per block
#define NTHR 512

// ---------------------------------------------------------------------------
// One-time converts: feat -> bf16 row-major; w_ih/w_hh -> bf16 in MFMA
// B-fragment-linear order: wb[(jt_glob*KB + kb)*64 + lane][i] holds
// W[jt_glob*16 + (lane&15)][kb*32 + (lane>>4)*8 + i].
// ---------------------------------------------------------------------------
__global__ __launch_bounds__(256) void conv_kernel(
    const float* __restrict__ feat, const float* __restrict__ w_ih,
    const float* __restrict__ w_hh,
    unsigned short* __restrict__ featb, unsigned short* __restrict__ wbi,
    unsigned short* __restrict__ wbh, int nfeat8)
{
    int t = blockIdx.x * 256 + threadIdx.x;
    if (t < nfeat8) {
        u16x8 o;
        #pragma unroll
        for (int i = 0; i < 8; ++i) o[i] = f2bf(feat[(size_t)t * 8 + i]);
        *(u16x8*)&featb[(size_t)t * 8] = o;
    } else if (t < nfeat8 + 98304) {        // w_hh: 96 jt x 16 kb x 64 lanes
        int tt = t - nfeat8;
        int lane = tt & 63, q = tt >> 6;
        int jt = q >> 4, kb = q & 15;
        int j = jt * 16 + (lane & 15);
        int k0 = kb * 32 + (lane >> 4) * 8;
        u16x8 o;
        #pragma unroll
        for (int i = 0; i < 8; ++i) o[i] = f2bf(w_hh[(size_t)j * 512 + k0 + i]);
        *(u16x8*)&wbh[(size_t)tt * 8] = o;
    } else if (t < nfeat8 + 98304 + 12288) { // w_ih: 96 jt x 2 kb x 64 lanes
        int uu = t - nfeat8 - 98304;
        int lane = uu & 63, q = uu >> 6;
        int jt = q >> 1, kb = q & 1;
        int j = jt * 16 + (lane & 15);
        int k0 = kb * 32 + (lane >> 4) * 8;
        u16x8 o;
        #pragma unroll
        for (int i = 0; i < 8; ++i) o[i] = f2bf(w_ih[(size_t)j * 64 + k0 + i]);
        *(u16x8*)&wbi[(size_t)uu * 8] = o;
    }
}

// ---------------------------------------------------------------------------
// GRU via mfma_f32_16x16x32_bf16.  Block = 128 edges, 512 threads (8 waves).
// Wave w owns j in [w*64, w*64+64) for ALL 128 edges (m = 8 edge-blocks of 16
// -> each 3-load weight group feeds 24 MFMAs, 2x the R4 ratio).
// h state: single 128 KB LDS buffer (bf16, XOR-swizzled).  Between steps h
// round-trips through global (first 1 KB of each edge's 2 KB eft row; block-
// private; fp32 eft overwrites only at l==3).  Stores drain at barrier;
// restage uses volatile (sc0) loads -> L2 coherence point.
// ---------------------------------------------------------------------------
__global__ __launch_bounds__(NTHR, 2) void gru_mfma_kernel(
    const unsigned short* __restrict__ featb,
    const int* __restrict__ emi,
    const unsigned short* __restrict__ wbi,
    const unsigned short* __restrict__ wbh,
    const float* __restrict__ b_ih,
    const float* __restrict__ b_hh,
    float* __restrict__ eft,
    int E)
{
    __shared__ unsigned short hb[EB * 512];  // 128 KB, single buffer
    __shared__ unsigned short xb[EB * 64];   // 16 KB

    const int tid  = threadIdx.x;
    const int lane = tid & 63;
    const int w    = tid >> 6;       // 0..7
    const int g    = lane >> 4;
    const int c    = lane & 15;
    const int e0   = blockIdx.x * EB;
    const f32x4 fzero = {0.f, 0.f, 0.f, 0.f};

    for (int l = 0; l < 4; ++l) {
        // ---- stage x: 128 rows x 128 B, 512 threads -> 4 thr/row x 32 B ----
        {
            int r = tid >> 2, p = tid & 3;
            int nidx = (e0 + r < E) ? emi[(e0 + r) * 4 + l] : 0;
            const unsigned short* src = featb + (size_t)nidx * 64 + p * 16;
            u16x8 v0 = *(const u16x8*)(src);
            u16x8 v1 = *(const u16x8*)(src + 8);
            int sw = (r & 7) << 3;
            *(u16x8*)&xb[r * 64 + ((p * 16 + 0) ^ sw)] = v0;
            *(u16x8*)&xb[r * 64 + ((p * 16 + 8) ^ sw)] = v1;
        }
        // ---- restage h from global (l>0): 8192 16B-chunks / 512 thr = 16 ----
        if (l > 0) {
            #pragma unroll
            for (int it = 0; it < 16; ++it) {
                int q = it * 512 + tid;
                int row = q >> 6, col8 = q & 63;
                const volatile unsigned* hsrc =
                    (const volatile unsigned*)((const char*)eft + (size_t)(e0 + row) * 2048) + (col8 << 2);
                unsigned u0 = hsrc[0], u1 = hsrc[1], u2 = hsrc[2], u3 = hsrc[3];
                uint4 v = {u0, u1, u2, u3};
                *(uint4*)&hb[row * 512 + (((col8 << 3)) ^ ((row & 7) << 3))] = v;
            }
        }
        __syncthreads();

        for (int cc = 0; cc < 4; ++cc) {
            const int j0 = (w << 6) + (cc << 4);
            const int jt = j0 >> 4;           // 0..31 within a gate block
            f32x4 ar[8], az[8], ain[8], ahn[8];
            #pragma unroll
            for (int m = 0; m < 8; ++m) { ar[m] = fzero; az[m] = fzero; ain[m] = fzero; ahn[m] = fzero; }

            // ---- gi = x . W_ih^T  (K=64) ----
            #pragma unroll
            for (int kb = 0; kb < 2; ++kb) {
                bf16x8 br = *(const bf16x8*)(wbi + (((size_t)((jt     ) * 2 + kb)) * 64 + lane) * 8);
                bf16x8 bz = *(const bf16x8*)(wbi + (((size_t)((32 + jt) * 2 + kb)) * 64 + lane) * 8);
                bf16x8 bn = *(const bf16x8*)(wbi + (((size_t)((64 + jt) * 2 + kb)) * 64 + lane) * 8);
                #pragma unroll
                for (int m = 0; m < 8; ++m) {
                    int row = m * 16 + c;
                    bf16x8 a = *(const bf16x8*)&xb[row * 64 + ((kb * 32 + g * 8) ^ ((row & 7) << 3))];
                    ar[m]  = __builtin_amdgcn_mfma_f32_16x16x32_bf16(a, br, ar[m], 0, 0, 0);
                    az[m]  = __builtin_amdgcn_mfma_f32_16x16x32_bf16(a, bz, az[m], 0, 0, 0);
                    ain[m] = __builtin_amdgcn_mfma_f32_16x16x32_bf16(a, bn, ain[m], 0, 0, 0);
                }
            }
            // ---- gh = h . W_hh^T  (K=512); h==0 at l==0 ----
            if (l > 0) {
                #pragma unroll 2
                for (int kb = 0; kb < 16; ++kb) {
                    bf16x8 br = *(const bf16x8*)(wbh + (((size_t)((jt     ) * 16 + kb)) * 64 + lane) * 8);
                    bf16x8 bz = *(const bf16x8*)(wbh + (((size_t)((32 + jt) * 16 + kb)) * 64 + lane) * 8);
                    bf16x8 bn = *(const bf16x8*)(wbh + (((size_t)((64 + jt) * 16 + kb)) * 64 + lane) * 8);
                    #pragma unroll
                    for (int m = 0; m < 8; ++m) {
                        int row = m * 16 + c;
                        bf16x8 a = *(const bf16x8*)&hb[row * 512 + ((kb * 32 + g * 8) ^ ((row & 7) << 3))];
                        ar[m]  = __builtin_amdgcn_mfma_f32_16x16x32_bf16(a, br, ar[m], 0, 0, 0);
                        az[m]  = __builtin_amdgcn_mfma_f32_16x16x32_bf16(a, bz, az[m], 0, 0, 0);
                        ahn[m] = __builtin_amdgcn_mfma_f32_16x16x32_bf16(a, bn, ahn[m], 0, 0, 0);
                    }
                }
            }
            // ---- gate combine (fp32) ----
            const int j = j0 + c;
            const float brr = b_ih[j] + b_hh[j];
            const float bzz = b_ih[512 + j] + b_hh[512 + j];
            const float bin = b_ih[1024 + j];
            const float bhn = b_hh[1024 + j];
            #pragma unroll
            for (int m = 0; m < 8; ++m) {
                #pragma unroll
                for (int q = 0; q < 4; ++q) {
                    int row = m * 16 + g * 4 + q;
                    float hold = (l > 0) ? bf2f(hb[row * 512 + (j ^ ((row & 7) << 3))]) : 0.f;
                    float r  = 1.f / (1.f + __expf(-(ar[m][q] + brr)));
                    float z  = 1.f / (1.f + __expf(-(az[m][q] + bzz)));
                    float pn = ain[m][q] + bin + r * (ahn[m][q] + bhn);
                    float ex = __expf(-2.f * pn);
                    float n  = (1.f - ex) / (1.f + ex);         // tanh
                    float hnew = (1.f - z) * n + z * hold;
                    int e = e0 + row;
                    if (e < E) {
                        if (l < 3) {
                            unsigned short* hrow = (unsigned short*)((char*)eft + (size_t)e * 2048);
                            hrow[j] = f2bf(hnew);
                        } else {
                            eft[(size_t)e * 512 + j] = hnew;
                        }
                    }
                }
            }
        }
        __syncthreads();   // h_new stores drained (vmcnt 0) before restage reads
    }
}

// ---------------------------------------------------------------------------
__global__ __launch_bounds__(256) void attn_kernel(
    const float* __restrict__ eft, const float* __restrict__ attn,
    const int* __restrict__ dst, float* __restrict__ aexp,
    float* __restrict__ denom, int E)
{
    int gidx = blockIdx.x * 256 + threadIdx.x;
    if (gidx >= E * 8) return;
    int e = gidx >> 3, h = gidx & 7;
    const float* fp = &eft[(size_t)e * 512 + (h << 6)];
    const float* ap = &attn[h << 6];
    float a = 0.f;
    #pragma unroll
    for (int k = 0; k < 16; ++k) {
        float4 f = *(const float4*)(fp + (k << 2));
        float4 wv = *(const float4*)(ap + (k << 2));
        a += f.x * wv.x + f.y * wv.y + f.z * wv.z + f.w * wv.w;
    }
    a = (a > 0.f) ? a : 0.001f * a;   // leaky relu
    float ae = __expf(a);             // no max-sub: logits O(1), ratio identical
    aexp[gidx] = ae;
    atomicAdd(&denom[(size_t)dst[e] * 8 + h], ae);
}

__global__ __launch_bounds__(256) void scatter_kernel(
    const float* __restrict__ eft, const float* __restrict__ aexp,
    const float* __restrict__ denom, const int* __restrict__ dst,
    float* __restrict__ out, long long total)
{
    long long gi = (long long)blockIdx.x * 256 + threadIdx.x;
    if (gi >= total) return;
    int e = (int)(gi >> 9);
    int j = (int)(gi & 511);
    int h = j >> 6;
    int n = dst[e];
    float wv = aexp[(size_t)e * 8 + h] / fmaxf(denom[(size_t)n * 8 + h], 1e-12f);
    atomicAdd(&out[(size_t)n * 512 + j], eft[gi] * wv);
}

// ---------------------------------------------------------------------------
extern "C" void kernel_launch(void* const* d_in, const int* in_sizes, int n_in,
                              void* d_out, int out_size, void* d_ws, size_t ws_size,
                              hipStream_t stream)
{
    const float* feat = (const float*)d_in[0];
    const int*   emi  = (const int*)d_in[1];
    const int*   dst  = (const int*)d_in[2];
    const float* w_ih = (const float*)d_in[4];
    const float* w_hh = (const float*)d_in[5];
    const float* b_ih = (const float*)d_in[6];
    const float* b_hh = (const float*)d_in[7];
    const float* attn = (const float*)d_in[8];

    const int E = in_sizes[1] / 4;
    const int N = out_size / 512;
    const int nfeat8 = in_sizes[0] / 8;

    float* eft = (float*)d_ws;                                   // E*512 f32 (h scratch in row heads)
    unsigned short* featb = (unsigned short*)(eft + (size_t)E * 512);
    unsigned short* wbi   = featb + (size_t)(in_sizes[0]);       // nfeat*64 u16
    unsigned short* wbh   = wbi + (size_t)96 * 2 * 64 * 8;
    // post-GRU aliases (featb/wbi/wbh dead after gru):
    float* aexp  = (float*)featb;            // E*8 f32
    float* denom = aexp + (size_t)E * 8;     // N*8 f32
    float* out   = (float*)d_out;

    int conv_total = nfeat8 + 98304 + 12288;
    conv_kernel<<<(conv_total + 255) / 256, 256, 0, stream>>>(
        feat, w_ih, w_hh, featb, wbi, wbh, nfeat8);

    gru_mfma_kernel<<<(E + EB - 1) / EB, NTHR, 0, stream>>>(
        featb, emi, wbi, wbh, b_ih, b_hh, eft, E);

    // denom aliases workspace tail -> zero AFTER gru consumed weights
    (void)hipMemsetAsync(denom, 0, (size_t)N * 8 * sizeof(float), stream);
    (void)hipMemsetAsync(d_out, 0, (size_t)out_size * sizeof(float), stream);

    attn_kernel<<<(E * 8 + 255) / 256, 256, 0, stream>>>(eft, attn, dst, aexp, denom, E);

    long long total = (long long)E * 512;
    scatter_kernel<<<(int)((total + 255) / 256), 256, 0, stream>>>(
        eft, aexp, denom, dst, out, total);
}

// Round 8
// 1509.417 us; speedup vs baseline: 1.5462x; 1.5462x over previous
//
#include <hip/hip_runtime.h>
#include <cstdint>

typedef __attribute__((ext_vector_type(8))) short          bf16x8;
typedef __attribute__((ext_vector_type(8))) unsigned short u16x8;
typedef __attribute__((ext_vector_type(4))) float          f32x4;

__device__ __forceinline__ unsigned short f2bf(float x) {
    union { float f; unsigned u; } v; v.f = x;
    unsigned r = v.u + 0x7FFF + ((v.u >> 16) & 1);   // RNE
    return (unsigned short)(r >> 16);
}
__device__ __forceinline__ float bf2f(unsigned short b) {
    union { float f; unsigned u; } v; v.u = ((unsigned)b) << 16;
    return v.f;
}

#define EB   64
#define NTHR 512

// ---------------------------------------------------------------------------
// One-time converts: feat -> bf16 row-major; w_ih/w_hh -> bf16 in MFMA
// B-fragment-linear order: wb[(jt_glob*KB + kb)*64 + lane][i] holds
// W[jt_glob*16 + (lane&15)][kb*32 + (lane>>4)*8 + i].
// ---------------------------------------------------------------------------
__global__ __launch_bounds__(256) void conv_kernel(
    const float* __restrict__ feat, const float* __restrict__ w_ih,
    const float* __restrict__ w_hh,
    unsigned short* __restrict__ featb, unsigned short* __restrict__ wbi,
    unsigned short* __restrict__ wbh, int nfeat8)
{
    int t = blockIdx.x * 256 + threadIdx.x;
    if (t < nfeat8) {
        u16x8 o;
        #pragma unroll
        for (int i = 0; i < 8; ++i) o[i] = f2bf(feat[(size_t)t * 8 + i]);
        *(u16x8*)&featb[(size_t)t * 8] = o;
    } else if (t < nfeat8 + 98304) {        // w_hh: 96 jt x 16 kb x 64 lanes
        int tt = t - nfeat8;
        int lane = tt & 63, q = tt >> 6;
        int jt = q >> 4, kb = q & 15;
        int j = jt * 16 + (lane & 15);
        int k0 = kb * 32 + (lane >> 4) * 8;
        u16x8 o;
        #pragma unroll
        for (int i = 0; i < 8; ++i) o[i] = f2bf(w_hh[(size_t)j * 512 + k0 + i]);
        *(u16x8*)&wbh[(size_t)tt * 8] = o;
    } else if (t < nfeat8 + 98304 + 12288) { // w_ih: 96 jt x 2 kb x 64 lanes
        int uu = t - nfeat8 - 98304;
        int lane = uu & 63, q = uu >> 6;
        int jt = q >> 1, kb = q & 1;
        int j = jt * 16 + (lane & 15);
        int k0 = kb * 32 + (lane >> 4) * 8;
        u16x8 o;
        #pragma unroll
        for (int i = 0; i < 8; ++i) o[i] = f2bf(w_ih[(size_t)j * 64 + k0 + i]);
        *(u16x8*)&wbi[(size_t)uu * 8] = o;
    }
}

// ---------------------------------------------------------------------------
// GRU via mfma_f32_16x16x32_bf16.  Block = 64 edges, 512 threads (8 waves).
// Wave w owns j in [w*64, w*64+64) for ALL 64 edges.
// h state: DOUBLE-buffered bf16 LDS (2 x 64 KB, XOR-swizzled) -> zero global
// h traffic (R4/R5's 1.5-2 GB HBM h round-trip eliminated).  136 KB LDS ->
// 1 block/CU, 2 waves/SIMD; L2 latency on the weight B-fragments is covered
// by an explicit 2-deep prefetch (slots rotated on kb&1, fully unrolled so
// all indexing is compile-time).
// ---------------------------------------------------------------------------
__global__ __launch_bounds__(NTHR, 2) void gru_mfma_kernel(
    const unsigned short* __restrict__ featb,
    const int* __restrict__ emi,
    const unsigned short* __restrict__ wbi,
    const unsigned short* __restrict__ wbh,
    const float* __restrict__ b_ih,
    const float* __restrict__ b_hh,
    float* __restrict__ eft,
    int E)
{
    __shared__ unsigned short hb[2][EB * 512];  // 128 KB
    __shared__ unsigned short xb[EB * 64];      // 8 KB

    const int tid  = threadIdx.x;
    const int lane = tid & 63;
    const int w    = tid >> 6;       // 0..7
    const int g    = lane >> 4;
    const int c    = lane & 15;
    const int e0   = blockIdx.x * EB;
    const f32x4 fzero = {0.f, 0.f, 0.f, 0.f};

    for (int l = 0; l < 4; ++l) {
        const int rbuf = (l + 1) & 1;   // l=1 reads 0, l=2 reads 1, l=3 reads 0
        const int wbuf = l & 1;         // l=0 writes 0, l=1 writes 1, l=2 writes 0
        // ---- stage x: 64 rows x 128 B, 512 threads -> 8 thr/row x 16 B ----
        {
            int r = tid >> 3, p = tid & 7;
            int nidx = (e0 + r < E) ? emi[(e0 + r) * 4 + l] : 0;
            u16x8 v = *(const u16x8*)(featb + (size_t)nidx * 64 + p * 8);
            *(u16x8*)&xb[r * 64 + ((p * 8) ^ ((r & 7) << 3))] = v;
        }
        __syncthreads();

        for (int cc = 0; cc < 4; ++cc) {
            const int j0 = (w << 6) + (cc << 4);
            const int jt = j0 >> 4;           // 0..31 within a gate block
            f32x4 ar[4], az[4], ain[4], ahn[4];
            #pragma unroll
            for (int m = 0; m < 4; ++m) { ar[m] = fzero; az[m] = fzero; ain[m] = fzero; ahn[m] = fzero; }

            // ---- gi = x . W_ih^T  (K=64): 6 frag loads up front ----
            {
                bf16x8 r0 = *(const bf16x8*)(wbi + (((size_t)((jt     ) * 2 + 0)) * 64 + lane) * 8);
                bf16x8 r1 = *(const bf16x8*)(wbi + (((size_t)((jt     ) * 2 + 1)) * 64 + lane) * 8);
                bf16x8 z0 = *(const bf16x8*)(wbi + (((size_t)((32 + jt) * 2 + 0)) * 64 + lane) * 8);
                bf16x8 z1 = *(const bf16x8*)(wbi + (((size_t)((32 + jt) * 2 + 1)) * 64 + lane) * 8);
                bf16x8 n0 = *(const bf16x8*)(wbi + (((size_t)((64 + jt) * 2 + 0)) * 64 + lane) * 8);
                bf16x8 n1 = *(const bf16x8*)(wbi + (((size_t)((64 + jt) * 2 + 1)) * 64 + lane) * 8);
                #pragma unroll
                for (int m = 0; m < 4; ++m) {
                    int row = m * 16 + c;
                    bf16x8 a0 = *(const bf16x8*)&xb[row * 64 + ((g * 8) ^ ((row & 7) << 3))];
                    ar[m]  = __builtin_amdgcn_mfma_f32_16x16x32_bf16(a0, r0, ar[m], 0, 0, 0);
                    az[m]  = __builtin_amdgcn_mfma_f32_16x16x32_bf16(a0, z0, az[m], 0, 0, 0);
                    ain[m] = __builtin_amdgcn_mfma_f32_16x16x32_bf16(a0, n0, ain[m], 0, 0, 0);
                    bf16x8 a1 = *(const bf16x8*)&xb[row * 64 + ((32 + g * 8) ^ ((row & 7) << 3))];
                    ar[m]  = __builtin_amdgcn_mfma_f32_16x16x32_bf16(a1, r1, ar[m], 0, 0, 0);
                    az[m]  = __builtin_amdgcn_mfma_f32_16x16x32_bf16(a1, z1, az[m], 0, 0, 0);
                    ain[m] = __builtin_amdgcn_mfma_f32_16x16x32_bf16(a1, n1, ain[m], 0, 0, 0);
                }
            }
            // ---- gh = h . W_hh^T (K=512, l>0): 2-deep prefetched kb loop ----
            if (l > 0) {
                const unsigned short* hrow = &hb[rbuf][0];
                bf16x8 pr[2], pz[2], pn[2];
                pr[0] = *(const bf16x8*)(wbh + (((size_t)((jt     ) * 16 + 0)) * 64 + lane) * 8);
                pr[1] = *(const bf16x8*)(wbh + (((size_t)((jt     ) * 16 + 1)) * 64 + lane) * 8);
                pz[0] = *(const bf16x8*)(wbh + (((size_t)((32 + jt) * 16 + 0)) * 64 + lane) * 8);
                pz[1] = *(const bf16x8*)(wbh + (((size_t)((32 + jt) * 16 + 1)) * 64 + lane) * 8);
                pn[0] = *(const bf16x8*)(wbh + (((size_t)((64 + jt) * 16 + 0)) * 64 + lane) * 8);
                pn[1] = *(const bf16x8*)(wbh + (((size_t)((64 + jt) * 16 + 1)) * 64 + lane) * 8);
                #pragma unroll
                for (int kb = 0; kb < 16; ++kb) {
                    const int cur = kb & 1;
                    bf16x8 br = pr[cur], bz = pz[cur], bn = pn[cur];
                    if (kb + 2 < 16) {   // issue kb+2 loads before kb's MFMAs
                        pr[cur] = *(const bf16x8*)(wbh + (((size_t)((jt     ) * 16 + kb + 2)) * 64 + lane) * 8);
                        pz[cur] = *(const bf16x8*)(wbh + (((size_t)((32 + jt) * 16 + kb + 2)) * 64 + lane) * 8);
                        pn[cur] = *(const bf16x8*)(wbh + (((size_t)((64 + jt) * 16 + kb + 2)) * 64 + lane) * 8);
                    }
                    #pragma unroll
                    for (int m = 0; m < 4; ++m) {
                        int row = m * 16 + c;
                        bf16x8 a = *(const bf16x8*)&hrow[row * 512 + ((kb * 32 + g * 8) ^ ((row & 7) << 3))];
                        ar[m]  = __builtin_amdgcn_mfma_f32_16x16x32_bf16(a, br, ar[m], 0, 0, 0);
                        az[m]  = __builtin_amdgcn_mfma_f32_16x16x32_bf16(a, bz, az[m], 0, 0, 0);
                        ahn[m] = __builtin_amdgcn_mfma_f32_16x16x32_bf16(a, bn, ahn[m], 0, 0, 0);
                    }
                }
            }
            // ---- gate combine (fp32) ----
            const int j = j0 + c;
            const float brr = b_ih[j] + b_hh[j];
            const float bzz = b_ih[512 + j] + b_hh[512 + j];
            const float bin = b_ih[1024 + j];
            const float bhn = b_hh[1024 + j];
            #pragma unroll
            for (int m = 0; m < 4; ++m) {
                #pragma unroll
                for (int q = 0; q < 4; ++q) {
                    int row = m * 16 + g * 4 + q;
                    float hold = (l > 0) ? bf2f(hb[rbuf][row * 512 + (j ^ ((row & 7) << 3))]) : 0.f;
                    float r  = 1.f / (1.f + __expf(-(ar[m][q] + brr)));
                    float z  = 1.f / (1.f + __expf(-(az[m][q] + bzz)));
                    float pn2 = ain[m][q] + bin + r * (ahn[m][q] + bhn);
                    float ex = __expf(-2.f * pn2);
                    float n  = (1.f - ex) / (1.f + ex);         // tanh
                    float hnew = (1.f - z) * n + z * hold;
                    if (l < 3) {
                        hb[wbuf][row * 512 + (j ^ ((row & 7) << 3))] = f2bf(hnew);
                    } else {
                        int e = e0 + row;
                        if (e < E) eft[(size_t)e * 512 + j] = hnew;
                    }
                }
            }
        }
        __syncthreads();   // hb[wbuf]/xb writes visible before next step
    }
}

// ---------------------------------------------------------------------------
__global__ __launch_bounds__(256) void attn_kernel(
    const float* __restrict__ eft, const float* __restrict__ attn,
    const int* __restrict__ dst, float* __restrict__ aexp,
    float* __restrict__ denom, int E)
{
    int gidx = blockIdx.x * 256 + threadIdx.x;
    if (gidx >= E * 8) return;
    int e = gidx >> 3, h = gidx & 7;
    const float* fp = &eft[(size_t)e * 512 + (h << 6)];
    const float* ap = &attn[h << 6];
    float a = 0.f;
    #pragma unroll
    for (int k = 0; k < 16; ++k) {
        float4 f = *(const float4*)(fp + (k << 2));
        float4 wv = *(const float4*)(ap + (k << 2));
        a += f.x * wv.x + f.y * wv.y + f.z * wv.z + f.w * wv.w;
    }
    a = (a > 0.f) ? a : 0.001f * a;   // leaky relu
    float ae = __expf(a);             // no max-sub: logits O(1), ratio identical
    aexp[gidx] = ae;
    atomicAdd(&denom[(size_t)dst[e] * 8 + h], ae);
}

__global__ __launch_bounds__(256) void scatter_kernel(
    const float* __restrict__ eft, const float* __restrict__ aexp,
    const float* __restrict__ denom, const int* __restrict__ dst,
    float* __restrict__ out, long long total)
{
    long long gi = (long long)blockIdx.x * 256 + threadIdx.x;
    if (gi >= total) return;
    int e = (int)(gi >> 9);
    int j = (int)(gi & 511);
    int h = j >> 6;
    int n = dst[e];
    float wv = aexp[(size_t)e * 8 + h] / fmaxf(denom[(size_t)n * 8 + h], 1e-12f);
    atomicAdd(&out[(size_t)n * 512 + j], eft[gi] * wv);
}

// ---------------------------------------------------------------------------
extern "C" void kernel_launch(void* const* d_in, const int* in_sizes, int n_in,
                              void* d_out, int out_size, void* d_ws, size_t ws_size,
                              hipStream_t stream)
{
    const float* feat = (const float*)d_in[0];
    const int*   emi  = (const int*)d_in[1];
    const int*   dst  = (const int*)d_in[2];
    const float* w_ih = (const float*)d_in[4];
    const float* w_hh = (const float*)d_in[5];
    const float* b_ih = (const float*)d_in[6];
    const float* b_hh = (const float*)d_in[7];
    const float* attn = (const float*)d_in[8];

    const int E = in_sizes[1] / 4;
    const int N = out_size / 512;
    const int nfeat8 = in_sizes[0] / 8;

    float* eft = (float*)d_ws;                                   // E*512 f32
    unsigned short* featb = (unsigned short*)(eft + (size_t)E * 512);
    unsigned short* wbi   = featb + (size_t)(in_sizes[0]);       // nfeat*64 u16
    unsigned short* wbh   = wbi + (size_t)96 * 2 * 64 * 8;
    // post-GRU aliases (featb/wbi/wbh dead after gru):
    float* aexp  = (float*)featb;            // E*8 f32
    float* denom = aexp + (size_t)E * 8;     // N*8 f32
    float* out   = (float*)d_out;

    int conv_total = nfeat8 + 98304 + 12288;
    conv_kernel<<<(conv_total + 255) / 256, 256, 0, stream>>>(
        feat, w_ih, w_hh, featb, wbi, wbh, nfeat8);

    gru_mfma_kernel<<<(E + EB - 1) / EB, NTHR, 0, stream>>>(
        featb, emi, wbi, wbh, b_ih, b_hh, eft, E);

    // denom aliases workspace tail -> zero AFTER gru consumed weights
    (void)hipMemsetAsync(denom, 0, (size_t)N * 8 * sizeof(float), stream);
    (void)hipMemsetAsync(d_out, 0, (size_t)out_size * sizeof(float), stream);

    attn_kernel<<<(E * 8 + 255) / 256, 256, 0, stream>>>(eft, attn, dst, aexp, denom, E);

    long long total = (long long)E * 512;
    scatter_kernel<<<(int)((total + 255) / 256), 256, 0, stream>>>(
        eft, aexp, denom, dst, out, total);
}